// Round 9
// baseline (252.642 us; speedup 1.0000x reference)
//
#include <hip/hip_runtime.h>

typedef __attribute__((ext_vector_type(4))) float f32x4;
typedef __attribute__((ext_vector_type(8))) short s16x8;
typedef __attribute__((ext_vector_type(4))) short s16x4;
typedef __bf16 bf16x4 __attribute__((ext_vector_type(4)));

#define B_   96
#define NQ   35
#define LP   180
#define H_   768
#define D_   128
#define NEGF (-1e30f)

#define NROWS 37920
#define QROWS 3360
#define PROWS 17280

__device__ __forceinline__ unsigned short f2bf(float f) {
    return __builtin_bit_cast(unsigned short, (__bf16)f);
}

__device__ __forceinline__ s16x8 pack_bf16(f32x4 v0, f32x4 v1) {
    bf16x4 h0 = __builtin_convertvector(v0, bf16x4);
    bf16x4 h1 = __builtin_convertvector(v1, bf16x4);
    s16x4 a = __builtin_bit_cast(s16x4, h0), b = __builtin_bit_cast(s16x4, h1);
    return __builtin_shufflevector(a, b, 0, 1, 2, 3, 4, 5, 6, 7);
}

// async global->LDS, 16 B per lane; lds dest must be wave-uniform (HW adds lane*16)
__device__ __forceinline__ void glds16(const void* g, void* l) {
    __builtin_amdgcn_global_load_lds(
        (const __attribute__((address_space(1))) unsigned int*)g,
        (__attribute__((address_space(3))) unsigned int*)l,
        16, 0, 0);
}

// ---------------- prep: wt_build (blocks 0-47) + mask canon w/ local detect (48-182) ----
__global__ __launch_bounds__(256) void prep_k(
    const float* __restrict__ W, unsigned short* __restrict__ wthi,
    const void* __restrict__ pm, const void* __restrict__ nm,
    unsigned char* __restrict__ maskc) {
    __shared__ unsigned int rr[256];
    int b = blockIdx.x, t = threadIdx.x;
    if (b < 48) {
        int tid = b * 256 + t;
        int nt = tid / (24 * 64);
        int r = tid - nt * 24 * 64;
        int ks = r / 64, lane = r - ks * 64;
        int m = lane & 15, quad = lane >> 4;
        unsigned short* o = wthi + (size_t)tid * 8;
#pragma unroll
        for (int j = 0; j < 8; j++) {
            int k = ks * 32 + quad * 8 + j;
            o[j] = f2bf(W[(size_t)k * D_ + nt * 16 + m]);
        }
    } else {
        const unsigned int* pw = (const unsigned int*)pm;
        unsigned int f1 = 0, f3 = 0, f4 = 0;
        for (int w = t; w < 4320; w += 256) {
            unsigned int v = pw[w];
            f1 |= v & 0x0000ff00u;                 // byte %4==1 -> 1-byte layout
            f3 |= v & 0xff000000u;                 // byte %4==3 -> float32
            if (w & 1) f4 |= v & 0x000000ffu;      // byte %8==4 -> int32
        }
        rr[t] = f1; __syncthreads();
        for (int s2 = 128; s2; s2 >>= 1) { if (t < s2) rr[t] |= rr[t + s2]; __syncthreads(); }
        unsigned int c1 = rr[0]; __syncthreads();
        rr[t] = f3; __syncthreads();
        for (int s2 = 128; s2; s2 >>= 1) { if (t < s2) rr[t] |= rr[t + s2]; __syncthreads(); }
        unsigned int c3 = rr[0]; __syncthreads();
        rr[t] = f4; __syncthreads();
        for (int s2 = 128; s2; s2 >>= 1) { if (t < s2) rr[t] |= rr[t + s2]; __syncthreads(); }
        unsigned int c4 = rr[0];
        int i = (b - 48) * 256 + t;                // < 34560 exactly (135 blocks)
        const void* src = (i < B_ * LP) ? pm : nm;
        int j = (i < B_ * LP) ? i : i - B_ * LP;
        bool bit;
        if (c1 > 0)       bit = ((const unsigned char*)src)[j] != 0;
        else if (c3 > 0)  bit = ((const float*)src)[j] != 0.0f;
        else if (c4 > 0)  bit = ((const int*)src)[j] != 0;
        else              bit = ((const long long*)src)[j] != 0;
        maskc[i] = bit ? 1 : 0;
    }
}

// ---------------- proj v10: passage-fused proj+normalize+scatter (unchanged from R8) ----
__global__ __launch_bounds__(512, 1) void proj_k(
    const float* __restrict__ qh, const float* __restrict__ ph, const float* __restrict__ nh,
    const unsigned short* __restrict__ wthi, const float* __restrict__ bias,
    const unsigned char* __restrict__ maskc,
    unsigned short* __restrict__ qfrag, unsigned short* __restrict__ pfrag) {
    __shared__ float sb[24576];                      // 96 KB: 2 x 192 x 64 f32 staging
    int b = blockIdx.x, t = threadIdx.x;
    int wave = t >> 6, lane = t & 63;
    int m = lane & 15, quad = lane >> 4;
    unsigned short* xb = (unsigned short*)sb;        // post-loop transpose buffer

    if (b < 192) {
        const float* src = (b < 96) ? ph + (size_t)b * LP * H_
                                    : nh + (size_t)(b - 96) * LP * H_;
        const float* gp[6];
#pragma unroll
        for (int g = 0; g < 6; g++) {
            int rl = wave * 24 + g * 4 + (lane >> 4);
            int rc = rl < LP ? rl : LP - 1;
            gp[g] = src + (size_t)rc * H_ + (((lane & 15) ^ (2 * (rl & 7))) << 2);
        }

        f32x4 acc[12];
#pragma unroll
        for (int mt = 0; mt < 12; mt++) acc[mt] = (f32x4){0.f, 0.f, 0.f, 0.f};

        {
            float* d0 = sb + wave * 1536;
#pragma unroll
            for (int g = 0; g < 6; g++) glds16(gp[g], d0 + g * 256);
        }
        __syncthreads();

        for (int s = 0; s < 12; s++) {
            if (s < 11) {
                float* d0 = sb + ((s + 1) & 1) * 12288 + wave * 1536;
#pragma unroll
                for (int g = 0; g < 6; g++) glds16(gp[g] + (s + 1) * 64, d0 + g * 256);
            }
            const float* bb = sb + (s & 1) * 12288;
#pragma unroll
            for (int ksg = 0; ksg < 2; ksg++) {
                s16x8 bf = *(const s16x8*)(wthi +
                           ((size_t)(wave * 24 + s * 2 + ksg) * 64 + lane) * 8);
                int kc = ksg * 8 + quad * 2;
#pragma unroll
                for (int mt = 0; mt < 12; mt++) {
                    int row = mt * 16 + m;
                    const float* fb = bb + row * 64 + ((kc ^ (2 * (row & 7))) << 2);
                    f32x4 lo = *(const f32x4*)fb, hi = *(const f32x4*)(fb + 4);
                    acc[mt] = __builtin_amdgcn_mfma_f32_16x16x32_bf16(
                        pack_bf16(lo, hi), bf, acc[mt], 0, 0, 0);
                }
            }
            __syncthreads();
        }

        float bv = bias[wave * 16 + m];
        float s2 = 0.f;
#pragma unroll
        for (int mt = 0; mt < 12; mt++)
#pragma unroll
            for (int r = 0; r < 4; r++) {
                int prow = mt * 16 + quad * 4 + r;
                float v = acc[mt][r] + bv;
                acc[mt][r] = v;
                if (prow < LP) s2 += v * v;
            }
        s2 += __shfl_xor(s2, 16); s2 += __shfl_xor(s2, 32);
        float sc = rsqrtf(fmaxf(s2, 1e-24f));
        __syncthreads();
#pragma unroll
        for (int mt = 0; mt < 12; mt++)
#pragma unroll
            for (int r = 0; r < 4; r++) {
                int prow = mt * 16 + quad * 4 + r;
                if (prow < LP) xb[prow * 136 + wave * 16 + m] = f2bf(acc[mt][r] * sc);
            }
        __syncthreads();
        const unsigned char* mk = maskc + b * LP;
        unsigned short* pdst = pfrag + (size_t)b * 24576;
#pragma unroll
        for (int i = 0; i < 6; i++) {
            int ch = t + i * 512;
            int ln = ch & 63;
            int l = ((ch >> 8) << 4) + (ln & 15);
            int lsrc = (l < LP && mk[l]) ? l : 0;
            int d0 = ((ch >> 6) & 3) * 32 + (ln >> 4) * 8;
            *(s16x8*)&pdst[(size_t)ch * 8] = *(const s16x8*)&xb[lsrc * 136 + d0];
        }
    } else {
        int qp = b - 192;                            // [0,48)
        const float* src = qh + (size_t)qp * 70 * H_;
        const float* gp[3];
#pragma unroll
        for (int g = 0; g < 3; g++) {
            int rl = wave * 12 + g * 4 + (lane >> 4);
            int rc = rl < 70 ? rl : 69;
            gp[g] = src + (size_t)rc * H_ + (((lane & 15) ^ (2 * (rl & 7))) << 2);
        }

        f32x4 acc[5];
#pragma unroll
        for (int mt = 0; mt < 5; mt++) acc[mt] = (f32x4){0.f, 0.f, 0.f, 0.f};

        {
            float* d0 = sb + wave * 768;
#pragma unroll
            for (int g = 0; g < 3; g++) glds16(gp[g], d0 + g * 256);
        }
        __syncthreads();

        for (int s = 0; s < 12; s++) {
            if (s < 11) {
                float* d0 = sb + ((s + 1) & 1) * 6144 + wave * 768;
#pragma unroll
                for (int g = 0; g < 3; g++) glds16(gp[g] + (s + 1) * 64, d0 + g * 256);
            }
            const float* bb = sb + (s & 1) * 6144;
#pragma unroll
            for (int ksg = 0; ksg < 2; ksg++) {
                s16x8 bf = *(const s16x8*)(wthi +
                           ((size_t)(wave * 24 + s * 2 + ksg) * 64 + lane) * 8);
                int kc = ksg * 8 + quad * 2;
#pragma unroll
                for (int mt = 0; mt < 5; mt++) {
                    int row = mt * 16 + m;
                    const float* fb = bb + row * 64 + ((kc ^ (2 * (row & 7))) << 2);
                    f32x4 lo = *(const f32x4*)fb, hi = *(const f32x4*)(fb + 4);
                    acc[mt] = __builtin_amdgcn_mfma_f32_16x16x32_bf16(
                        pack_bf16(lo, hi), bf, acc[mt], 0, 0, 0);
                }
            }
            __syncthreads();
        }

        float bv = bias[wave * 16 + m];
        float s0 = 0.f, s1 = 0.f;
#pragma unroll
        for (int mt = 0; mt < 5; mt++)
#pragma unroll
            for (int r = 0; r < 4; r++) {
                int prow = mt * 16 + quad * 4 + r;
                float v = acc[mt][r] + bv;
                acc[mt][r] = v;
                if (prow < 35) s0 += v * v;
                else if (prow < 70) s1 += v * v;
            }
        s0 += __shfl_xor(s0, 16); s0 += __shfl_xor(s0, 32);
        s1 += __shfl_xor(s1, 16); s1 += __shfl_xor(s1, 32);
        float sc0 = rsqrtf(fmaxf(s0, 1e-24f));
        float sc1 = rsqrtf(fmaxf(s1, 1e-24f));
        __syncthreads();
#pragma unroll
        for (int mt = 0; mt < 5; mt++)
#pragma unroll
            for (int r = 0; r < 4; r++) {
                int prow = mt * 16 + quad * 4 + r;
                if (prow < 70)
                    xb[prow * 136 + wave * 16 + m] =
                        f2bf(acc[mt][r] * (prow < 35 ? sc0 : sc1));
            }
        __syncthreads();
        unsigned short* qdst = qfrag + (size_t)qp * 10240;
#pragma unroll
        for (int i = 0; i < 3; i++) {
            int ch = t + i * 512;
            if (ch < 1280) {
                int ln = ch & 63;
                int prow = ((ch >> 8) << 4) + (ln & 15);
                int d0 = ((ch >> 6) & 3) * 32 + (ln >> 4) * 8;
                s16x8 v = (s16x8){0, 0, 0, 0, 0, 0, 0, 0};
                if (prow < 70) v = *(const s16x8*)&xb[prow * 136 + d0];
                *(s16x8*)&qdst[(size_t)ch * 8] = v;
            }
        }
    }
}

// ---------------- interact v2: 4 qg-groups per staged p-block, setprio on MFMA ----------
// R8 accounting: total - proj has been ~144-150 us ALL SESSION while scatter deletion
// moved it ~4 us -> interact_k (never surfaced in the top-5 table, which only showed
// proj_k rows) owns the bulk. v2 reuses each staged p-block (48 KB LDS) across THREE
// passes of q-groups: 768 blocks instead of 2304 -> p-staging 110->37 MB, 3x fewer
// launch/ramp tails, LDS tile reused 12x. s_setprio(1) wraps each nt's MFMA cluster
// (T5: multi-wave independent-block regime, the attn-like case where it measured +).
// MFMA core, fragment layouts, reductions, out-mapping bit-identical; 768 blocks x
// 4 waves x 3 passes = 48 qp x 192 c covered exactly once.
__global__ __launch_bounds__(256, 3) void interact_k(
    const unsigned short* __restrict__ qfrag, const unsigned short* __restrict__ pfrag,
    float* __restrict__ out) {
    __shared__ unsigned short plds[24576];           // 48 KB, shared by all 4 waves
    int wave = threadIdx.x >> 6, lane = threadIdx.x & 63;
    int b = blockIdx.x;                              // 768 blocks
    int xcd = b & 7, i = b >> 3;                     // i in [0,96)
    int c = xcd * 24 + (i % 24);                     // [0,192)
    int qgg = i / 24;                                // [0,4)
    int side = c / 96, pb = c - side * 96;
    int m = lane & 15, quad = lane >> 4;

    const unsigned short* pbase = pfrag + (size_t)c * 24576;

#pragma unroll
    for (int ntl = 0; ntl < 3; ntl++) {
        int nt = wave * 3 + ntl;
#pragma unroll
        for (int ks = 0; ks < 4; ks++)
            glds16(pbase + ((size_t)(nt * 4 + ks) * 64 + lane) * 8,
                   &plds[(size_t)(nt * 4 + ks) * 512]);
    }
    __syncthreads();                                 // drain staging; plds read-only after

    const f32x4 zero4 = (f32x4){0.f, 0.f, 0.f, 0.f};

#pragma unroll 1
    for (int pass = 0; pass < 3; pass++) {
        int qp = (qgg * 3 + pass) * 4 + wave;        // [0,48)
        const unsigned short* qbase = qfrag + (size_t)qp * 10240;

        s16x8 a[5][4];
#pragma unroll
        for (int mt = 0; mt < 5; mt++)
#pragma unroll
            for (int ks = 0; ks < 4; ks++)
                a[mt][ks] = *(const s16x8*)(qbase + ((size_t)(mt * 4 + ks) * 64 + lane) * 8);

        float rmax[5][4];
#pragma unroll
        for (int mt = 0; mt < 5; mt++)
#pragma unroll
            for (int rr = 0; rr < 4; rr++) rmax[mt][rr] = NEGF;

        for (int nt = 0; nt < 12; nt++) {
            s16x8 bfr[4];
#pragma unroll
            for (int ks = 0; ks < 4; ks++)
                bfr[ks] = *(const s16x8*)&plds[((size_t)(nt * 4 + ks) * 64 + lane) * 8];
            __builtin_amdgcn_s_setprio(1);
#pragma unroll
            for (int mt = 0; mt < 5; mt++) {
                f32x4 acc = __builtin_amdgcn_mfma_f32_16x16x32_bf16(a[mt][0], bfr[0], zero4, 0, 0, 0);
                acc = __builtin_amdgcn_mfma_f32_16x16x32_bf16(a[mt][1], bfr[1], acc, 0, 0, 0);
                acc = __builtin_amdgcn_mfma_f32_16x16x32_bf16(a[mt][2], bfr[2], acc, 0, 0, 0);
                acc = __builtin_amdgcn_mfma_f32_16x16x32_bf16(a[mt][3], bfr[3], acc, 0, 0, 0);
#pragma unroll
                for (int rr = 0; rr < 4; rr++)
                    rmax[mt][rr] = fmaxf(rmax[mt][rr], acc[rr]);
            }
            __builtin_amdgcn_s_setprio(0);
        }

#pragma unroll
        for (int mt = 0; mt < 5; mt++)
#pragma unroll
            for (int rr = 0; rr < 4; rr++) {
                float v = rmax[mt][rr];
                v = fmaxf(v, __shfl_xor(v, 1));
                v = fmaxf(v, __shfl_xor(v, 2));
                v = fmaxf(v, __shfl_xor(v, 4));
                v = fmaxf(v, __shfl_xor(v, 8));
                rmax[mt][rr] = v;
            }
        float s0 = 0.f, s1 = 0.f;
#pragma unroll
        for (int mt = 0; mt < 5; mt++)
#pragma unroll
            for (int rr = 0; rr < 4; rr++) {
                int prow = mt * 16 + quad * 4 + rr;
                float v = rmax[mt][rr];
                if (prow < 35) s0 += v;
                else if (prow < 70) s1 += v;
            }
        s0 += __shfl_xor(s0, 16); s0 += __shfl_xor(s0, 32);
        s1 += __shfl_xor(s1, 16); s1 += __shfl_xor(s1, 32);
        if (lane == 0) {
            int qb0 = qp * 2, qb1 = qp * 2 + 1;
            out[(size_t)qb0 * (2 * B_) + side * B_ + pb] = s0;
            out[(size_t)qb1 * (2 * B_) + side * B_ + pb] = s1;
        }
    }
}

// ---------------- launch ----------------
extern "C" void kernel_launch(void* const* d_in, const int* in_sizes, int n_in,
                              void* d_out, int out_size, void* d_ws, size_t ws_size,
                              hipStream_t stream) {
    const float* qh   = (const float*)d_in[0];
    const float* ph   = (const float*)d_in[1];
    const float* nh   = (const float*)d_in[2];
    const float* W    = (const float*)d_in[3];
    const float* bias = (const float*)d_in[4];
    const void* pmask = d_in[5];
    const void* nmask = d_in[6];
    float* out = (float*)d_out;
    char* ws = (char*)d_ws;

    constexpr size_t WTHI_OFF  = 256;                        // 196608 B
    constexpr size_t MASKC_OFF = WTHI_OFF + 196608;          // 34560 B
    constexpr size_t QFRAG_OFF = MASKC_OFF + 34560;          // 983040 B
    constexpr size_t PFRAG_OFF = QFRAG_OFF + 983040;         // 9437184 B

    unsigned short* wthi   = (unsigned short*)(ws + WTHI_OFF);
    unsigned char* maskc   = (unsigned char*)(ws + MASKC_OFF);
    unsigned short* qfrag  = (unsigned short*)(ws + QFRAG_OFF);
    unsigned short* pfrag  = (unsigned short*)(ws + PFRAG_OFF);

    prep_k<<<183, 256, 0, stream>>>(W, wthi, pmask, nmask, maskc);
    proj_k<<<240, 512, 0, stream>>>(qh, ph, nh, wthi, bias, maskc, qfrag, pfrag);
    interact_k<<<768, 256, 0, stream>>>(qfrag, pfrag, out);
}

// Round 10
// 220.869 us; speedup vs baseline: 1.1439x; 1.1439x over previous
//
#include <hip/hip_runtime.h>

typedef __attribute__((ext_vector_type(4))) float f32x4;
typedef __attribute__((ext_vector_type(8))) short s16x8;
typedef __attribute__((ext_vector_type(4))) short s16x4;
typedef __bf16 bf16x4 __attribute__((ext_vector_type(4)));

#define B_   96
#define NQ   35
#define LP   180
#define H_   768
#define D_   128
#define NEGF (-1e30f)

#define NROWS 37920
#define QROWS 3360
#define PROWS 17280

__device__ __forceinline__ unsigned short f2bf(float f) {
    return __builtin_bit_cast(unsigned short, (__bf16)f);
}

__device__ __forceinline__ s16x8 pack_bf16(f32x4 v0, f32x4 v1) {
    bf16x4 h0 = __builtin_convertvector(v0, bf16x4);
    bf16x4 h1 = __builtin_convertvector(v1, bf16x4);
    s16x4 a = __builtin_bit_cast(s16x4, h0), b = __builtin_bit_cast(s16x4, h1);
    return __builtin_shufflevector(a, b, 0, 1, 2, 3, 4, 5, 6, 7);
}

// async global->LDS, 16 B per lane; lds dest must be wave-uniform (HW adds lane*16)
__device__ __forceinline__ void glds16(const void* g, void* l) {
    __builtin_amdgcn_global_load_lds(
        (const __attribute__((address_space(1))) unsigned int*)g,
        (__attribute__((address_space(3))) unsigned int*)l,
        16, 0, 0);
}

// ---------------- prep: wt_build (blocks 0-47) + mask canon w/ local detect (48-182) ----
__global__ __launch_bounds__(256) void prep_k(
    const float* __restrict__ W, unsigned short* __restrict__ wthi,
    const void* __restrict__ pm, const void* __restrict__ nm,
    unsigned char* __restrict__ maskc) {
    __shared__ unsigned int rr[256];
    int b = blockIdx.x, t = threadIdx.x;
    if (b < 48) {
        int tid = b * 256 + t;
        int nt = tid / (24 * 64);
        int r = tid - nt * 24 * 64;
        int ks = r / 64, lane = r - ks * 64;
        int m = lane & 15, quad = lane >> 4;
        unsigned short* o = wthi + (size_t)tid * 8;
#pragma unroll
        for (int j = 0; j < 8; j++) {
            int k = ks * 32 + quad * 8 + j;
            o[j] = f2bf(W[(size_t)k * D_ + nt * 16 + m]);
        }
    } else {
        const unsigned int* pw = (const unsigned int*)pm;
        unsigned int f1 = 0, f3 = 0, f4 = 0;
        for (int w = t; w < 4320; w += 256) {
            unsigned int v = pw[w];
            f1 |= v & 0x0000ff00u;                 // byte %4==1 -> 1-byte layout
            f3 |= v & 0xff000000u;                 // byte %4==3 -> float32
            if (w & 1) f4 |= v & 0x000000ffu;      // byte %8==4 -> int32
        }
        rr[t] = f1; __syncthreads();
        for (int s2 = 128; s2; s2 >>= 1) { if (t < s2) rr[t] |= rr[t + s2]; __syncthreads(); }
        unsigned int c1 = rr[0]; __syncthreads();
        rr[t] = f3; __syncthreads();
        for (int s2 = 128; s2; s2 >>= 1) { if (t < s2) rr[t] |= rr[t + s2]; __syncthreads(); }
        unsigned int c3 = rr[0]; __syncthreads();
        rr[t] = f4; __syncthreads();
        for (int s2 = 128; s2; s2 >>= 1) { if (t < s2) rr[t] |= rr[t + s2]; __syncthreads(); }
        unsigned int c4 = rr[0];
        int i = (b - 48) * 256 + t;                // < 34560 exactly (135 blocks)
        const void* src = (i < B_ * LP) ? pm : nm;
        int j = (i < B_ * LP) ? i : i - B_ * LP;
        bool bit;
        if (c1 > 0)       bit = ((const unsigned char*)src)[j] != 0;
        else if (c3 > 0)  bit = ((const float*)src)[j] != 0.0f;
        else if (c4 > 0)  bit = ((const int*)src)[j] != 0;
        else              bit = ((const long long*)src)[j] != 0;
        maskc[i] = bit ? 1 : 0;
    }
}

// ---------------- proj v10: passage-fused proj+normalize+scatter (unchanged from R8) ----
__global__ __launch_bounds__(512, 1) void proj_k(
    const float* __restrict__ qh, const float* __restrict__ ph, const float* __restrict__ nh,
    const unsigned short* __restrict__ wthi, const float* __restrict__ bias,
    const unsigned char* __restrict__ maskc,
    unsigned short* __restrict__ qfrag, unsigned short* __restrict__ pfrag) {
    __shared__ float sb[24576];                      // 96 KB: 2 x 192 x 64 f32 staging
    int b = blockIdx.x, t = threadIdx.x;
    int wave = t >> 6, lane = t & 63;
    int m = lane & 15, quad = lane >> 4;
    unsigned short* xb = (unsigned short*)sb;        // post-loop transpose buffer

    if (b < 192) {
        const float* src = (b < 96) ? ph + (size_t)b * LP * H_
                                    : nh + (size_t)(b - 96) * LP * H_;
        const float* gp[6];
#pragma unroll
        for (int g = 0; g < 6; g++) {
            int rl = wave * 24 + g * 4 + (lane >> 4);
            int rc = rl < LP ? rl : LP - 1;
            gp[g] = src + (size_t)rc * H_ + (((lane & 15) ^ (2 * (rl & 7))) << 2);
        }

        f32x4 acc[12];
#pragma unroll
        for (int mt = 0; mt < 12; mt++) acc[mt] = (f32x4){0.f, 0.f, 0.f, 0.f};

        {
            float* d0 = sb + wave * 1536;
#pragma unroll
            for (int g = 0; g < 6; g++) glds16(gp[g], d0 + g * 256);
        }
        __syncthreads();

        for (int s = 0; s < 12; s++) {
            if (s < 11) {
                float* d0 = sb + ((s + 1) & 1) * 12288 + wave * 1536;
#pragma unroll
                for (int g = 0; g < 6; g++) glds16(gp[g] + (s + 1) * 64, d0 + g * 256);
            }
            const float* bb = sb + (s & 1) * 12288;
#pragma unroll
            for (int ksg = 0; ksg < 2; ksg++) {
                s16x8 bf = *(const s16x8*)(wthi +
                           ((size_t)(wave * 24 + s * 2 + ksg) * 64 + lane) * 8);
                int kc = ksg * 8 + quad * 2;
#pragma unroll
                for (int mt = 0; mt < 12; mt++) {
                    int row = mt * 16 + m;
                    const float* fb = bb + row * 64 + ((kc ^ (2 * (row & 7))) << 2);
                    f32x4 lo = *(const f32x4*)fb, hi = *(const f32x4*)(fb + 4);
                    acc[mt] = __builtin_amdgcn_mfma_f32_16x16x32_bf16(
                        pack_bf16(lo, hi), bf, acc[mt], 0, 0, 0);
                }
            }
            __syncthreads();
        }

        float bv = bias[wave * 16 + m];
        float s2 = 0.f;
#pragma unroll
        for (int mt = 0; mt < 12; mt++)
#pragma unroll
            for (int r = 0; r < 4; r++) {
                int prow = mt * 16 + quad * 4 + r;
                float v = acc[mt][r] + bv;
                acc[mt][r] = v;
                if (prow < LP) s2 += v * v;
            }
        s2 += __shfl_xor(s2, 16); s2 += __shfl_xor(s2, 32);
        float sc = rsqrtf(fmaxf(s2, 1e-24f));
        __syncthreads();
#pragma unroll
        for (int mt = 0; mt < 12; mt++)
#pragma unroll
            for (int r = 0; r < 4; r++) {
                int prow = mt * 16 + quad * 4 + r;
                if (prow < LP) xb[prow * 136 + wave * 16 + m] = f2bf(acc[mt][r] * sc);
            }
        __syncthreads();
        const unsigned char* mk = maskc + b * LP;
        unsigned short* pdst = pfrag + (size_t)b * 24576;
#pragma unroll
        for (int i = 0; i < 6; i++) {
            int ch = t + i * 512;
            int ln = ch & 63;
            int l = ((ch >> 8) << 4) + (ln & 15);
            int lsrc = (l < LP && mk[l]) ? l : 0;
            int d0 = ((ch >> 6) & 3) * 32 + (ln >> 4) * 8;
            *(s16x8*)&pdst[(size_t)ch * 8] = *(const s16x8*)&xb[lsrc * 136 + d0];
        }
    } else {
        int qp = b - 192;                            // [0,48)
        const float* src = qh + (size_t)qp * 70 * H_;
        const float* gp[3];
#pragma unroll
        for (int g = 0; g < 3; g++) {
            int rl = wave * 12 + g * 4 + (lane >> 4);
            int rc = rl < 70 ? rl : 69;
            gp[g] = src + (size_t)rc * H_ + (((lane & 15) ^ (2 * (rl & 7))) << 2);
        }

        f32x4 acc[5];
#pragma unroll
        for (int mt = 0; mt < 5; mt++) acc[mt] = (f32x4){0.f, 0.f, 0.f, 0.f};

        {
            float* d0 = sb + wave * 768;
#pragma unroll
            for (int g = 0; g < 3; g++) glds16(gp[g], d0 + g * 256);
        }
        __syncthreads();

        for (int s = 0; s < 12; s++) {
            if (s < 11) {
                float* d0 = sb + ((s + 1) & 1) * 6144 + wave * 768;
#pragma unroll
                for (int g = 0; g < 3; g++) glds16(gp[g] + (s + 1) * 64, d0 + g * 256);
            }
            const float* bb = sb + (s & 1) * 6144;
#pragma unroll
            for (int ksg = 0; ksg < 2; ksg++) {
                s16x8 bf = *(const s16x8*)(wthi +
                           ((size_t)(wave * 24 + s * 2 + ksg) * 64 + lane) * 8);
                int kc = ksg * 8 + quad * 2;
#pragma unroll
                for (int mt = 0; mt < 5; mt++) {
                    int row = mt * 16 + m;
                    const float* fb = bb + row * 64 + ((kc ^ (2 * (row & 7))) << 2);
                    f32x4 lo = *(const f32x4*)fb, hi = *(const f32x4*)(fb + 4);
                    acc[mt] = __builtin_amdgcn_mfma_f32_16x16x32_bf16(
                        pack_bf16(lo, hi), bf, acc[mt], 0, 0, 0);
                }
            }
            __syncthreads();
        }

        float bv = bias[wave * 16 + m];
        float s0 = 0.f, s1 = 0.f;
#pragma unroll
        for (int mt = 0; mt < 5; mt++)
#pragma unroll
            for (int r = 0; r < 4; r++) {
                int prow = mt * 16 + quad * 4 + r;
                float v = acc[mt][r] + bv;
                acc[mt][r] = v;
                if (prow < 35) s0 += v * v;
                else if (prow < 70) s1 += v * v;
            }
        s0 += __shfl_xor(s0, 16); s0 += __shfl_xor(s0, 32);
        s1 += __shfl_xor(s1, 16); s1 += __shfl_xor(s1, 32);
        float sc0 = rsqrtf(fmaxf(s0, 1e-24f));
        float sc1 = rsqrtf(fmaxf(s1, 1e-24f));
        __syncthreads();
#pragma unroll
        for (int mt = 0; mt < 5; mt++)
#pragma unroll
            for (int r = 0; r < 4; r++) {
                int prow = mt * 16 + quad * 4 + r;
                if (prow < 70)
                    xb[prow * 136 + wave * 16 + m] =
                        f2bf(acc[mt][r] * (prow < 35 ? sc0 : sc1));
            }
        __syncthreads();
        unsigned short* qdst = qfrag + (size_t)qp * 10240;
#pragma unroll
        for (int i = 0; i < 3; i++) {
            int ch = t + i * 512;
            if (ch < 1280) {
                int ln = ch & 63;
                int prow = ((ch >> 8) << 4) + (ln & 15);
                int d0 = ((ch >> 6) & 3) * 32 + (ln >> 4) * 8;
                s16x8 v = (s16x8){0, 0, 0, 0, 0, 0, 0, 0};
                if (prow < 70) v = *(const s16x8*)&xb[prow * 136 + d0];
                *(s16x8*)&qdst[(size_t)ch * 8] = v;
            }
        }
    }
}

// ---------------- interact v3: v2 structure + SPILL FIX (launch_bounds 256,2) -----------
// R9 smoking gun: interact at launch_bounds(256,3) got an ~84-VGPR budget, but the live
// set (a[5][4]=80 + bfr=16 + rmax=20 + addr) needs ~135 -> q-fragments spilled to
// scratch. FETCH 213 MB + WRITE 134 MB (inputs are 10.4 MB!) = 355 MB of scratch
// traffic @3.8 TB/s = the 93 us; cold dispatch 178 us = scratch backing alloc. This
// bug predates R0 (v1 had the same array + bound) -- it WAS the hidden ~140 us.
// Fix: min-waves 2 -> 256-VGPR budget, everything stays in registers, zero scratch.
// Occupancy 2 blocks/CU (8 waves/CU) -- fine, kernel becomes MFMA/LDS-bound
// (floor ~15 us MFMA + overlapped LDS/HBM). All else byte-identical to R9's verified
// kernel: 768 blocks, p staged once / reused 3 passes, setprio MFMA cluster.
__global__ __launch_bounds__(256, 2) void interact_k(
    const unsigned short* __restrict__ qfrag, const unsigned short* __restrict__ pfrag,
    float* __restrict__ out) {
    __shared__ unsigned short plds[24576];           // 48 KB, shared by all 4 waves
    int wave = threadIdx.x >> 6, lane = threadIdx.x & 63;
    int b = blockIdx.x;                              // 768 blocks
    int xcd = b & 7, i = b >> 3;                     // i in [0,96)
    int c = xcd * 24 + (i % 24);                     // [0,192)
    int qgg = i / 24;                                // [0,4)
    int side = c / 96, pb = c - side * 96;
    int m = lane & 15, quad = lane >> 4;

    const unsigned short* pbase = pfrag + (size_t)c * 24576;

#pragma unroll
    for (int ntl = 0; ntl < 3; ntl++) {
        int nt = wave * 3 + ntl;
#pragma unroll
        for (int ks = 0; ks < 4; ks++)
            glds16(pbase + ((size_t)(nt * 4 + ks) * 64 + lane) * 8,
                   &plds[(size_t)(nt * 4 + ks) * 512]);
    }
    __syncthreads();                                 // drain staging; plds read-only after

    const f32x4 zero4 = (f32x4){0.f, 0.f, 0.f, 0.f};

#pragma unroll 1
    for (int pass = 0; pass < 3; pass++) {
        int qp = (qgg * 3 + pass) * 4 + wave;        // [0,48)
        const unsigned short* qbase = qfrag + (size_t)qp * 10240;

        s16x8 a[5][4];
#pragma unroll
        for (int mt = 0; mt < 5; mt++)
#pragma unroll
            for (int ks = 0; ks < 4; ks++)
                a[mt][ks] = *(const s16x8*)(qbase + ((size_t)(mt * 4 + ks) * 64 + lane) * 8);

        float rmax[5][4];
#pragma unroll
        for (int mt = 0; mt < 5; mt++)
#pragma unroll
            for (int rr = 0; rr < 4; rr++) rmax[mt][rr] = NEGF;

        for (int nt = 0; nt < 12; nt++) {
            s16x8 bfr[4];
#pragma unroll
            for (int ks = 0; ks < 4; ks++)
                bfr[ks] = *(const s16x8*)&plds[((size_t)(nt * 4 + ks) * 64 + lane) * 8];
            __builtin_amdgcn_s_setprio(1);
#pragma unroll
            for (int mt = 0; mt < 5; mt++) {
                f32x4 acc = __builtin_amdgcn_mfma_f32_16x16x32_bf16(a[mt][0], bfr[0], zero4, 0, 0, 0);
                acc = __builtin_amdgcn_mfma_f32_16x16x32_bf16(a[mt][1], bfr[1], acc, 0, 0, 0);
                acc = __builtin_amdgcn_mfma_f32_16x16x32_bf16(a[mt][2], bfr[2], acc, 0, 0, 0);
                acc = __builtin_amdgcn_mfma_f32_16x16x32_bf16(a[mt][3], bfr[3], acc, 0, 0, 0);
#pragma unroll
                for (int rr = 0; rr < 4; rr++)
                    rmax[mt][rr] = fmaxf(rmax[mt][rr], acc[rr]);
            }
            __builtin_amdgcn_s_setprio(0);
        }

#pragma unroll
        for (int mt = 0; mt < 5; mt++)
#pragma unroll
            for (int rr = 0; rr < 4; rr++) {
                float v = rmax[mt][rr];
                v = fmaxf(v, __shfl_xor(v, 1));
                v = fmaxf(v, __shfl_xor(v, 2));
                v = fmaxf(v, __shfl_xor(v, 4));
                v = fmaxf(v, __shfl_xor(v, 8));
                rmax[mt][rr] = v;
            }
        float s0 = 0.f, s1 = 0.f;
#pragma unroll
        for (int mt = 0; mt < 5; mt++)
#pragma unroll
            for (int rr = 0; rr < 4; rr++) {
                int prow = mt * 16 + quad * 4 + rr;
                float v = rmax[mt][rr];
                if (prow < 35) s0 += v;
                else if (prow < 70) s1 += v;
            }
        s0 += __shfl_xor(s0, 16); s0 += __shfl_xor(s0, 32);
        s1 += __shfl_xor(s1, 16); s1 += __shfl_xor(s1, 32);
        if (lane == 0) {
            int qb0 = qp * 2, qb1 = qp * 2 + 1;
            out[(size_t)qb0 * (2 * B_) + side * B_ + pb] = s0;
            out[(size_t)qb1 * (2 * B_) + side * B_ + pb] = s1;
        }
    }
}

// ---------------- launch ----------------
extern "C" void kernel_launch(void* const* d_in, const int* in_sizes, int n_in,
                              void* d_out, int out_size, void* d_ws, size_t ws_size,
                              hipStream_t stream) {
    const float* qh   = (const float*)d_in[0];
    const float* ph   = (const float*)d_in[1];
    const float* nh   = (const float*)d_in[2];
    const float* W    = (const float*)d_in[3];
    const float* bias = (const float*)d_in[4];
    const void* pmask = d_in[5];
    const void* nmask = d_in[6];
    float* out = (float*)d_out;
    char* ws = (char*)d_ws;

    constexpr size_t WTHI_OFF  = 256;                        // 196608 B
    constexpr size_t MASKC_OFF = WTHI_OFF + 196608;          // 34560 B
    constexpr size_t QFRAG_OFF = MASKC_OFF + 34560;          // 983040 B
    constexpr size_t PFRAG_OFF = QFRAG_OFF + 983040;         // 9437184 B

    unsigned short* wthi   = (unsigned short*)(ws + WTHI_OFF);
    unsigned char* maskc   = (unsigned char*)(ws + MASKC_OFF);
    unsigned short* qfrag  = (unsigned short*)(ws + QFRAG_OFF);
    unsigned short* pfrag  = (unsigned short*)(ws + PFRAG_OFF);

    prep_k<<<183, 256, 0, stream>>>(W, wthi, pmask, nmask, maskc);
    proj_k<<<240, 512, 0, stream>>>(qh, ph, nh, wthi, bias, maskc, qfrag, pfrag);
    interact_k<<<768, 256, 0, stream>>>(qfrag, pfrag, out);
}

// Round 11
// 193.829 us; speedup vs baseline: 1.3034x; 1.1395x over previous
//
#include <hip/hip_runtime.h>

typedef __attribute__((ext_vector_type(4))) float f32x4;
typedef __attribute__((ext_vector_type(8))) short s16x8;
typedef __attribute__((ext_vector_type(4))) short s16x4;
typedef __bf16 bf16x4 __attribute__((ext_vector_type(4)));

#define B_   96
#define NQ   35
#define LP   180
#define H_   768
#define D_   128
#define NEGF (-1e30f)

#define NROWS 37920
#define QROWS 3360
#define PROWS 17280

__device__ __forceinline__ unsigned short f2bf(float f) {
    return __builtin_bit_cast(unsigned short, (__bf16)f);
}

__device__ __forceinline__ s16x8 pack_bf16(f32x4 v0, f32x4 v1) {
    bf16x4 h0 = __builtin_convertvector(v0, bf16x4);
    bf16x4 h1 = __builtin_convertvector(v1, bf16x4);
    s16x4 a = __builtin_bit_cast(s16x4, h0), b = __builtin_bit_cast(s16x4, h1);
    return __builtin_shufflevector(a, b, 0, 1, 2, 3, 4, 5, 6, 7);
}

// async global->LDS, 16 B per lane; lds dest must be wave-uniform (HW adds lane*16)
__device__ __forceinline__ void glds16(const void* g, void* l) {
    __builtin_amdgcn_global_load_lds(
        (const __attribute__((address_space(1))) unsigned int*)g,
        (__attribute__((address_space(3))) unsigned int*)l,
        16, 0, 0);
}

// ---------------- prep: wt_build (blocks 0-47) + mask canon w/ local detect (48-182) ----
__global__ __launch_bounds__(256) void prep_k(
    const float* __restrict__ W, unsigned short* __restrict__ wthi,
    const void* __restrict__ pm, const void* __restrict__ nm,
    unsigned char* __restrict__ maskc) {
    __shared__ unsigned int rr[256];
    int b = blockIdx.x, t = threadIdx.x;
    if (b < 48) {
        int tid = b * 256 + t;
        int nt = tid / (24 * 64);
        int r = tid - nt * 24 * 64;
        int ks = r / 64, lane = r - ks * 64;
        int m = lane & 15, quad = lane >> 4;
        unsigned short* o = wthi + (size_t)tid * 8;
#pragma unroll
        for (int j = 0; j < 8; j++) {
            int k = ks * 32 + quad * 8 + j;
            o[j] = f2bf(W[(size_t)k * D_ + nt * 16 + m]);
        }
    } else {
        const unsigned int* pw = (const unsigned int*)pm;
        unsigned int f1 = 0, f3 = 0, f4 = 0;
        for (int w = t; w < 4320; w += 256) {
            unsigned int v = pw[w];
            f1 |= v & 0x0000ff00u;                 // byte %4==1 -> 1-byte layout
            f3 |= v & 0xff000000u;                 // byte %4==3 -> float32
            if (w & 1) f4 |= v & 0x000000ffu;      // byte %8==4 -> int32
        }
        rr[t] = f1; __syncthreads();
        for (int s2 = 128; s2; s2 >>= 1) { if (t < s2) rr[t] |= rr[t + s2]; __syncthreads(); }
        unsigned int c1 = rr[0]; __syncthreads();
        rr[t] = f3; __syncthreads();
        for (int s2 = 128; s2; s2 >>= 1) { if (t < s2) rr[t] |= rr[t + s2]; __syncthreads(); }
        unsigned int c3 = rr[0]; __syncthreads();
        rr[t] = f4; __syncthreads();
        for (int s2 = 128; s2; s2 >>= 1) { if (t < s2) rr[t] |= rr[t + s2]; __syncthreads(); }
        unsigned int c4 = rr[0];
        int i = (b - 48) * 256 + t;                // < 34560 exactly (135 blocks)
        const void* src = (i < B_ * LP) ? pm : nm;
        int j = (i < B_ * LP) ? i : i - B_ * LP;
        bool bit;
        if (c1 > 0)       bit = ((const unsigned char*)src)[j] != 0;
        else if (c3 > 0)  bit = ((const float*)src)[j] != 0.0f;
        else if (c4 > 0)  bit = ((const int*)src)[j] != 0;
        else              bit = ((const long long*)src)[j] != 0;
        maskc[i] = bit ? 1 : 0;
    }
}

// ---------------- proj v10: passage-fused proj+normalize+scatter (unchanged from R8) ----
__global__ __launch_bounds__(512, 1) void proj_k(
    const float* __restrict__ qh, const float* __restrict__ ph, const float* __restrict__ nh,
    const unsigned short* __restrict__ wthi, const float* __restrict__ bias,
    const unsigned char* __restrict__ maskc,
    unsigned short* __restrict__ qfrag, unsigned short* __restrict__ pfrag) {
    __shared__ float sb[24576];                      // 96 KB: 2 x 192 x 64 f32 staging
    int b = blockIdx.x, t = threadIdx.x;
    int wave = t >> 6, lane = t & 63;
    int m = lane & 15, quad = lane >> 4;
    unsigned short* xb = (unsigned short*)sb;        // post-loop transpose buffer

    if (b < 192) {
        const float* src = (b < 96) ? ph + (size_t)b * LP * H_
                                    : nh + (size_t)(b - 96) * LP * H_;
        const float* gp[6];
#pragma unroll
        for (int g = 0; g < 6; g++) {
            int rl = wave * 24 + g * 4 + (lane >> 4);
            int rc = rl < LP ? rl : LP - 1;
            gp[g] = src + (size_t)rc * H_ + (((lane & 15) ^ (2 * (rl & 7))) << 2);
        }

        f32x4 acc[12];
#pragma unroll
        for (int mt = 0; mt < 12; mt++) acc[mt] = (f32x4){0.f, 0.f, 0.f, 0.f};

        {
            float* d0 = sb + wave * 1536;
#pragma unroll
            for (int g = 0; g < 6; g++) glds16(gp[g], d0 + g * 256);
        }
        __syncthreads();

        for (int s = 0; s < 12; s++) {
            if (s < 11) {
                float* d0 = sb + ((s + 1) & 1) * 12288 + wave * 1536;
#pragma unroll
                for (int g = 0; g < 6; g++) glds16(gp[g] + (s + 1) * 64, d0 + g * 256);
            }
            const float* bb = sb + (s & 1) * 12288;
#pragma unroll
            for (int ksg = 0; ksg < 2; ksg++) {
                s16x8 bf = *(const s16x8*)(wthi +
                           ((size_t)(wave * 24 + s * 2 + ksg) * 64 + lane) * 8);
                int kc = ksg * 8 + quad * 2;
#pragma unroll
                for (int mt = 0; mt < 12; mt++) {
                    int row = mt * 16 + m;
                    const float* fb = bb + row * 64 + ((kc ^ (2 * (row & 7))) << 2);
                    f32x4 lo = *(const f32x4*)fb, hi = *(const f32x4*)(fb + 4);
                    acc[mt] = __builtin_amdgcn_mfma_f32_16x16x32_bf16(
                        pack_bf16(lo, hi), bf, acc[mt], 0, 0, 0);
                }
            }
            __syncthreads();
        }

        float bv = bias[wave * 16 + m];
        float s2 = 0.f;
#pragma unroll
        for (int mt = 0; mt < 12; mt++)
#pragma unroll
            for (int r = 0; r < 4; r++) {
                int prow = mt * 16 + quad * 4 + r;
                float v = acc[mt][r] + bv;
                acc[mt][r] = v;
                if (prow < LP) s2 += v * v;
            }
        s2 += __shfl_xor(s2, 16); s2 += __shfl_xor(s2, 32);
        float sc = rsqrtf(fmaxf(s2, 1e-24f));
        __syncthreads();
#pragma unroll
        for (int mt = 0; mt < 12; mt++)
#pragma unroll
            for (int r = 0; r < 4; r++) {
                int prow = mt * 16 + quad * 4 + r;
                if (prow < LP) xb[prow * 136 + wave * 16 + m] = f2bf(acc[mt][r] * sc);
            }
        __syncthreads();
        const unsigned char* mk = maskc + b * LP;
        unsigned short* pdst = pfrag + (size_t)b * 24576;
#pragma unroll
        for (int i = 0; i < 6; i++) {
            int ch = t + i * 512;
            int ln = ch & 63;
            int l = ((ch >> 8) << 4) + (ln & 15);
            int lsrc = (l < LP && mk[l]) ? l : 0;
            int d0 = ((ch >> 6) & 3) * 32 + (ln >> 4) * 8;
            *(s16x8*)&pdst[(size_t)ch * 8] = *(const s16x8*)&xb[lsrc * 136 + d0];
        }
    } else {
        int qp = b - 192;                            // [0,48)
        const float* src = qh + (size_t)qp * 70 * H_;
        const float* gp[3];
#pragma unroll
        for (int g = 0; g < 3; g++) {
            int rl = wave * 12 + g * 4 + (lane >> 4);
            int rc = rl < 70 ? rl : 69;
            gp[g] = src + (size_t)rc * H_ + (((lane & 15) ^ (2 * (rl & 7))) << 2);
        }

        f32x4 acc[5];
#pragma unroll
        for (int mt = 0; mt < 5; mt++) acc[mt] = (f32x4){0.f, 0.f, 0.f, 0.f};

        {
            float* d0 = sb + wave * 768;
#pragma unroll
            for (int g = 0; g < 3; g++) glds16(gp[g], d0 + g * 256);
        }
        __syncthreads();

        for (int s = 0; s < 12; s++) {
            if (s < 11) {
                float* d0 = sb + ((s + 1) & 1) * 6144 + wave * 768;
#pragma unroll
                for (int g = 0; g < 3; g++) glds16(gp[g] + (s + 1) * 64, d0 + g * 256);
            }
            const float* bb = sb + (s & 1) * 6144;
#pragma unroll
            for (int ksg = 0; ksg < 2; ksg++) {
                s16x8 bf = *(const s16x8*)(wthi +
                           ((size_t)(wave * 24 + s * 2 + ksg) * 64 + lane) * 8);
                int kc = ksg * 8 + quad * 2;
#pragma unroll
                for (int mt = 0; mt < 5; mt++) {
                    int row = mt * 16 + m;
                    const float* fb = bb + row * 64 + ((kc ^ (2 * (row & 7))) << 2);
                    f32x4 lo = *(const f32x4*)fb, hi = *(const f32x4*)(fb + 4);
                    acc[mt] = __builtin_amdgcn_mfma_f32_16x16x32_bf16(
                        pack_bf16(lo, hi), bf, acc[mt], 0, 0, 0);
                }
            }
            __syncthreads();
        }

        float bv = bias[wave * 16 + m];
        float s0 = 0.f, s1 = 0.f;
#pragma unroll
        for (int mt = 0; mt < 5; mt++)
#pragma unroll
            for (int r = 0; r < 4; r++) {
                int prow = mt * 16 + quad * 4 + r;
                float v = acc[mt][r] + bv;
                acc[mt][r] = v;
                if (prow < 35) s0 += v * v;
                else if (prow < 70) s1 += v * v;
            }
        s0 += __shfl_xor(s0, 16); s0 += __shfl_xor(s0, 32);
        s1 += __shfl_xor(s1, 16); s1 += __shfl_xor(s1, 32);
        float sc0 = rsqrtf(fmaxf(s0, 1e-24f));
        float sc1 = rsqrtf(fmaxf(s1, 1e-24f));
        __syncthreads();
#pragma unroll
        for (int mt = 0; mt < 5; mt++)
#pragma unroll
            for (int r = 0; r < 4; r++) {
                int prow = mt * 16 + quad * 4 + r;
                if (prow < 70)
                    xb[prow * 136 + wave * 16 + m] =
                        f2bf(acc[mt][r] * (prow < 35 ? sc0 : sc1));
            }
        __syncthreads();
        unsigned short* qdst = qfrag + (size_t)qp * 10240;
#pragma unroll
        for (int i = 0; i < 3; i++) {
            int ch = t + i * 512;
            if (ch < 1280) {
                int ln = ch & 63;
                int prow = ((ch >> 8) << 4) + (ln & 15);
                int d0 = ((ch >> 6) & 3) * 32 + (ln >> 4) * 8;
                s16x8 v = (s16x8){0, 0, 0, 0, 0, 0, 0, 0};
                if (prow < 70) v = *(const s16x8*)&xb[prow * 136 + d0];
                *(s16x8*)&qdst[(size_t)ch * 8] = v;
            }
        }
    }
}

// ---------------- interact v4: mt-SPLIT to fit the allocator's 128-VGPR budget ----------
// R10 post-mortem: launch_bounds(256,2) raised the budget to 128 (not 256 -- allocator
// heuristic), still ~8-10 regs short of the ~135 live set -> residual spill (WRITE_SIZE
// 66 MB vs 73 KB output). Lesson: don't fight the allocator, shrink the live set.
// v4 splits each pass's 5 mt-tiles into {0..2} and {3..4}, each with its own full
// nt-sweep: peak live = a[3][4](48) + bfr(16) + rmax(12) + acc(4) + addr ~= 95 VGPR.
// Cost: p-tile LDS reads x2 (~12 us @69 TB/s, overlapped with ~15 us MFMA). Reduction
// order preserved (mt ascending, same shfl tree, same prow mapping) -> absmax unchanged.
// Structure otherwise identical to R9/R10: 768 blocks, p staged once / 3 passes,
// setprio around MFMA clusters.
__global__ __launch_bounds__(256, 2) void interact_k(
    const unsigned short* __restrict__ qfrag, const unsigned short* __restrict__ pfrag,
    float* __restrict__ out) {
    __shared__ unsigned short plds[24576];           // 48 KB, shared by all 4 waves
    int wave = threadIdx.x >> 6, lane = threadIdx.x & 63;
    int b = blockIdx.x;                              // 768 blocks
    int xcd = b & 7, i = b >> 3;                     // i in [0,96)
    int c = xcd * 24 + (i % 24);                     // [0,192)
    int qgg = i / 24;                                // [0,4)
    int side = c / 96, pb = c - side * 96;
    int m = lane & 15, quad = lane >> 4;

    const unsigned short* pbase = pfrag + (size_t)c * 24576;

#pragma unroll
    for (int ntl = 0; ntl < 3; ntl++) {
        int nt = wave * 3 + ntl;
#pragma unroll
        for (int ks = 0; ks < 4; ks++)
            glds16(pbase + ((size_t)(nt * 4 + ks) * 64 + lane) * 8,
                   &plds[(size_t)(nt * 4 + ks) * 512]);
    }
    __syncthreads();                                 // drain staging; plds read-only after

    const f32x4 zero4 = (f32x4){0.f, 0.f, 0.f, 0.f};

#pragma unroll 1
    for (int pass = 0; pass < 3; pass++) {
        int qp = (qgg * 3 + pass) * 4 + wave;        // [0,48)
        const unsigned short* qbase = qfrag + (size_t)qp * 10240;
        float s0 = 0.f, s1 = 0.f;

        // ---------- half A: mt 0..2 (live: a 48 + bfr 16 + rmax 12 VGPR) ----------
        {
            s16x8 a[3][4];
#pragma unroll
            for (int mt = 0; mt < 3; mt++)
#pragma unroll
                for (int ks = 0; ks < 4; ks++)
                    a[mt][ks] = *(const s16x8*)(qbase +
                                ((size_t)(mt * 4 + ks) * 64 + lane) * 8);
            float rmax[3][4];
#pragma unroll
            for (int mt = 0; mt < 3; mt++)
#pragma unroll
                for (int rr = 0; rr < 4; rr++) rmax[mt][rr] = NEGF;

            for (int nt = 0; nt < 12; nt++) {
                s16x8 bfr[4];
#pragma unroll
                for (int ks = 0; ks < 4; ks++)
                    bfr[ks] = *(const s16x8*)&plds[((size_t)(nt * 4 + ks) * 64 + lane) * 8];
                __builtin_amdgcn_s_setprio(1);
#pragma unroll
                for (int mt = 0; mt < 3; mt++) {
                    f32x4 acc = __builtin_amdgcn_mfma_f32_16x16x32_bf16(a[mt][0], bfr[0], zero4, 0, 0, 0);
                    acc = __builtin_amdgcn_mfma_f32_16x16x32_bf16(a[mt][1], bfr[1], acc, 0, 0, 0);
                    acc = __builtin_amdgcn_mfma_f32_16x16x32_bf16(a[mt][2], bfr[2], acc, 0, 0, 0);
                    acc = __builtin_amdgcn_mfma_f32_16x16x32_bf16(a[mt][3], bfr[3], acc, 0, 0, 0);
#pragma unroll
                    for (int rr = 0; rr < 4; rr++)
                        rmax[mt][rr] = fmaxf(rmax[mt][rr], acc[rr]);
                }
                __builtin_amdgcn_s_setprio(0);
            }
#pragma unroll
            for (int mt = 0; mt < 3; mt++)
#pragma unroll
                for (int rr = 0; rr < 4; rr++) {
                    float v = rmax[mt][rr];
                    v = fmaxf(v, __shfl_xor(v, 1));
                    v = fmaxf(v, __shfl_xor(v, 2));
                    v = fmaxf(v, __shfl_xor(v, 4));
                    v = fmaxf(v, __shfl_xor(v, 8));
                    int prow = mt * 16 + quad * 4 + rr;
                    if (prow < 35) s0 += v;
                    else if (prow < 70) s1 += v;
                }
        }

        // ---------- half B: mt 3..4 (live: a 32 + bfr 16 + rmax 8 VGPR) ----------
        {
            s16x8 a[2][4];
#pragma unroll
            for (int mt = 0; mt < 2; mt++)
#pragma unroll
                for (int ks = 0; ks < 4; ks++)
                    a[mt][ks] = *(const s16x8*)(qbase +
                                ((size_t)((mt + 3) * 4 + ks) * 64 + lane) * 8);
            float rmax[2][4];
#pragma unroll
            for (int mt = 0; mt < 2; mt++)
#pragma unroll
                for (int rr = 0; rr < 4; rr++) rmax[mt][rr] = NEGF;

            for (int nt = 0; nt < 12; nt++) {
                s16x8 bfr[4];
#pragma unroll
                for (int ks = 0; ks < 4; ks++)
                    bfr[ks] = *(const s16x8*)&plds[((size_t)(nt * 4 + ks) * 64 + lane) * 8];
                __builtin_amdgcn_s_setprio(1);
#pragma unroll
                for (int mt = 0; mt < 2; mt++) {
                    f32x4 acc = __builtin_amdgcn_mfma_f32_16x16x32_bf16(a[mt][0], bfr[0], zero4, 0, 0, 0);
                    acc = __builtin_amdgcn_mfma_f32_16x16x32_bf16(a[mt][1], bfr[1], acc, 0, 0, 0);
                    acc = __builtin_amdgcn_mfma_f32_16x16x32_bf16(a[mt][2], bfr[2], acc, 0, 0, 0);
                    acc = __builtin_amdgcn_mfma_f32_16x16x32_bf16(a[mt][3], bfr[3], acc, 0, 0, 0);
#pragma unroll
                    for (int rr = 0; rr < 4; rr++)
                        rmax[mt][rr] = fmaxf(rmax[mt][rr], acc[rr]);
                }
                __builtin_amdgcn_s_setprio(0);
            }
#pragma unroll
            for (int mt = 0; mt < 2; mt++)
#pragma unroll
                for (int rr = 0; rr < 4; rr++) {
                    float v = rmax[mt][rr];
                    v = fmaxf(v, __shfl_xor(v, 1));
                    v = fmaxf(v, __shfl_xor(v, 2));
                    v = fmaxf(v, __shfl_xor(v, 4));
                    v = fmaxf(v, __shfl_xor(v, 8));
                    int prow = (mt + 3) * 16 + quad * 4 + rr;
                    if (prow < 35) s0 += v;
                    else if (prow < 70) s1 += v;
                }
        }

        s0 += __shfl_xor(s0, 16); s0 += __shfl_xor(s0, 32);
        s1 += __shfl_xor(s1, 16); s1 += __shfl_xor(s1, 32);
        if (lane == 0) {
            int qb0 = qp * 2, qb1 = qp * 2 + 1;
            out[(size_t)qb0 * (2 * B_) + side * B_ + pb] = s0;
            out[(size_t)qb1 * (2 * B_) + side * B_ + pb] = s1;
        }
    }
}

// ---------------- launch ----------------
extern "C" void kernel_launch(void* const* d_in, const int* in_sizes, int n_in,
                              void* d_out, int out_size, void* d_ws, size_t ws_size,
                              hipStream_t stream) {
    const float* qh   = (const float*)d_in[0];
    const float* ph   = (const float*)d_in[1];
    const float* nh   = (const float*)d_in[2];
    const float* W    = (const float*)d_in[3];
    const float* bias = (const float*)d_in[4];
    const void* pmask = d_in[5];
    const void* nmask = d_in[6];
    float* out = (float*)d_out;
    char* ws = (char*)d_ws;

    constexpr size_t WTHI_OFF  = 256;                        // 196608 B
    constexpr size_t MASKC_OFF = WTHI_OFF + 196608;          // 34560 B
    constexpr size_t QFRAG_OFF = MASKC_OFF + 34560;          // 983040 B
    constexpr size_t PFRAG_OFF = QFRAG_OFF + 983040;         // 9437184 B

    unsigned short* wthi   = (unsigned short*)(ws + WTHI_OFF);
    unsigned char* maskc   = (unsigned char*)(ws + MASKC_OFF);
    unsigned short* qfrag  = (unsigned short*)(ws + QFRAG_OFF);
    unsigned short* pfrag  = (unsigned short*)(ws + PFRAG_OFF);

    prep_k<<<183, 256, 0, stream>>>(W, wthi, pmask, nmask, maskc);
    proj_k<<<240, 512, 0, stream>>>(qh, ph, nh, wthi, bias, maskc, qfrag, pfrag);
    interact_k<<<768, 256, 0, stream>>>(qfrag, pfrag, out);
}

// Round 12
// 188.386 us; speedup vs baseline: 1.3411x; 1.0289x over previous
//
#include <hip/hip_runtime.h>

typedef __attribute__((ext_vector_type(4))) float f32x4;
typedef __attribute__((ext_vector_type(8))) short s16x8;
typedef __attribute__((ext_vector_type(4))) short s16x4;
typedef __bf16 bf16x4 __attribute__((ext_vector_type(4)));

#define B_   96
#define NQ   35
#define LP   180
#define H_   768
#define D_   128
#define NEGF (-1e30f)

#define NROWS 37920
#define QROWS 3360
#define PROWS 17280

__device__ __forceinline__ unsigned short f2bf(float f) {
    return __builtin_bit_cast(unsigned short, (__bf16)f);
}

__device__ __forceinline__ s16x8 pack_bf16(f32x4 v0, f32x4 v1) {
    bf16x4 h0 = __builtin_convertvector(v0, bf16x4);
    bf16x4 h1 = __builtin_convertvector(v1, bf16x4);
    s16x4 a = __builtin_bit_cast(s16x4, h0), b = __builtin_bit_cast(s16x4, h1);
    return __builtin_shufflevector(a, b, 0, 1, 2, 3, 4, 5, 6, 7);
}

// async global->LDS, 16 B per lane; lds dest must be wave-uniform (HW adds lane*16)
__device__ __forceinline__ void glds16(const void* g, void* l) {
    __builtin_amdgcn_global_load_lds(
        (const __attribute__((address_space(1))) unsigned int*)g,
        (__attribute__((address_space(3))) unsigned int*)l,
        16, 0, 0);
}

// ---------------- prep: wt_build (blocks 0-47) + mask canon w/ local detect (48-182) ----
__global__ __launch_bounds__(256) void prep_k(
    const float* __restrict__ W, unsigned short* __restrict__ wthi,
    const void* __restrict__ pm, const void* __restrict__ nm,
    unsigned char* __restrict__ maskc) {
    __shared__ unsigned int rr[256];
    int b = blockIdx.x, t = threadIdx.x;
    if (b < 48) {
        int tid = b * 256 + t;
        int nt = tid / (24 * 64);
        int r = tid - nt * 24 * 64;
        int ks = r / 64, lane = r - ks * 64;
        int m = lane & 15, quad = lane >> 4;
        unsigned short* o = wthi + (size_t)tid * 8;
#pragma unroll
        for (int j = 0; j < 8; j++) {
            int k = ks * 32 + quad * 8 + j;
            o[j] = f2bf(W[(size_t)k * D_ + nt * 16 + m]);
        }
    } else {
        const unsigned int* pw = (const unsigned int*)pm;
        unsigned int f1 = 0, f3 = 0, f4 = 0;
        for (int w = t; w < 4320; w += 256) {
            unsigned int v = pw[w];
            f1 |= v & 0x0000ff00u;                 // byte %4==1 -> 1-byte layout
            f3 |= v & 0xff000000u;                 // byte %4==3 -> float32
            if (w & 1) f4 |= v & 0x000000ffu;      // byte %8==4 -> int32
        }
        rr[t] = f1; __syncthreads();
        for (int s2 = 128; s2; s2 >>= 1) { if (t < s2) rr[t] |= rr[t + s2]; __syncthreads(); }
        unsigned int c1 = rr[0]; __syncthreads();
        rr[t] = f3; __syncthreads();
        for (int s2 = 128; s2; s2 >>= 1) { if (t < s2) rr[t] |= rr[t + s2]; __syncthreads(); }
        unsigned int c3 = rr[0]; __syncthreads();
        rr[t] = f4; __syncthreads();
        for (int s2 = 128; s2; s2 >>= 1) { if (t < s2) rr[t] |= rr[t + s2]; __syncthreads(); }
        unsigned int c4 = rr[0];
        int i = (b - 48) * 256 + t;                // < 34560 exactly (135 blocks)
        const void* src = (i < B_ * LP) ? pm : nm;
        int j = (i < B_ * LP) ? i : i - B_ * LP;
        bool bit;
        if (c1 > 0)       bit = ((const unsigned char*)src)[j] != 0;
        else if (c3 > 0)  bit = ((const float*)src)[j] != 0.0f;
        else if (c4 > 0)  bit = ((const int*)src)[j] != 0;
        else              bit = ((const long long*)src)[j] != 0;
        maskc[i] = bit ? 1 : 0;
    }
}

// ---------------- proj v10: passage-fused proj+normalize+scatter (unchanged from R8) ----
__global__ __launch_bounds__(512, 1) void proj_k(
    const float* __restrict__ qh, const float* __restrict__ ph, const float* __restrict__ nh,
    const unsigned short* __restrict__ wthi, const float* __restrict__ bias,
    const unsigned char* __restrict__ maskc,
    unsigned short* __restrict__ qfrag, unsigned short* __restrict__ pfrag) {
    __shared__ float sb[24576];                      // 96 KB: 2 x 192 x 64 f32 staging
    int b = blockIdx.x, t = threadIdx.x;
    int wave = t >> 6, lane = t & 63;
    int m = lane & 15, quad = lane >> 4;
    unsigned short* xb = (unsigned short*)sb;        // post-loop transpose buffer

    if (b < 192) {
        const float* src = (b < 96) ? ph + (size_t)b * LP * H_
                                    : nh + (size_t)(b - 96) * LP * H_;
        const float* gp[6];
#pragma unroll
        for (int g = 0; g < 6; g++) {
            int rl = wave * 24 + g * 4 + (lane >> 4);
            int rc = rl < LP ? rl : LP - 1;
            gp[g] = src + (size_t)rc * H_ + (((lane & 15) ^ (2 * (rl & 7))) << 2);
        }

        f32x4 acc[12];
#pragma unroll
        for (int mt = 0; mt < 12; mt++) acc[mt] = (f32x4){0.f, 0.f, 0.f, 0.f};

        {
            float* d0 = sb + wave * 1536;
#pragma unroll
            for (int g = 0; g < 6; g++) glds16(gp[g], d0 + g * 256);
        }
        __syncthreads();

        for (int s = 0; s < 12; s++) {
            if (s < 11) {
                float* d0 = sb + ((s + 1) & 1) * 12288 + wave * 1536;
#pragma unroll
                for (int g = 0; g < 6; g++) glds16(gp[g] + (s + 1) * 64, d0 + g * 256);
            }
            const float* bb = sb + (s & 1) * 12288;
#pragma unroll
            for (int ksg = 0; ksg < 2; ksg++) {
                s16x8 bf = *(const s16x8*)(wthi +
                           ((size_t)(wave * 24 + s * 2 + ksg) * 64 + lane) * 8);
                int kc = ksg * 8 + quad * 2;
#pragma unroll
                for (int mt = 0; mt < 12; mt++) {
                    int row = mt * 16 + m;
                    const float* fb = bb + row * 64 + ((kc ^ (2 * (row & 7))) << 2);
                    f32x4 lo = *(const f32x4*)fb, hi = *(const f32x4*)(fb + 4);
                    acc[mt] = __builtin_amdgcn_mfma_f32_16x16x32_bf16(
                        pack_bf16(lo, hi), bf, acc[mt], 0, 0, 0);
                }
            }
            __syncthreads();
        }

        float bv = bias[wave * 16 + m];
        float s2 = 0.f;
#pragma unroll
        for (int mt = 0; mt < 12; mt++)
#pragma unroll
            for (int r = 0; r < 4; r++) {
                int prow = mt * 16 + quad * 4 + r;
                float v = acc[mt][r] + bv;
                acc[mt][r] = v;
                if (prow < LP) s2 += v * v;
            }
        s2 += __shfl_xor(s2, 16); s2 += __shfl_xor(s2, 32);
        float sc = rsqrtf(fmaxf(s2, 1e-24f));
        __syncthreads();
#pragma unroll
        for (int mt = 0; mt < 12; mt++)
#pragma unroll
            for (int r = 0; r < 4; r++) {
                int prow = mt * 16 + quad * 4 + r;
                if (prow < LP) xb[prow * 136 + wave * 16 + m] = f2bf(acc[mt][r] * sc);
            }
        __syncthreads();
        const unsigned char* mk = maskc + b * LP;
        unsigned short* pdst = pfrag + (size_t)b * 24576;
#pragma unroll
        for (int i = 0; i < 6; i++) {
            int ch = t + i * 512;
            int ln = ch & 63;
            int l = ((ch >> 8) << 4) + (ln & 15);
            int lsrc = (l < LP && mk[l]) ? l : 0;
            int d0 = ((ch >> 6) & 3) * 32 + (ln >> 4) * 8;
            *(s16x8*)&pdst[(size_t)ch * 8] = *(const s16x8*)&xb[lsrc * 136 + d0];
        }
    } else {
        int qp = b - 192;                            // [0,48)
        const float* src = qh + (size_t)qp * 70 * H_;
        const float* gp[3];
#pragma unroll
        for (int g = 0; g < 3; g++) {
            int rl = wave * 12 + g * 4 + (lane >> 4);
            int rc = rl < 70 ? rl : 69;
            gp[g] = src + (size_t)rc * H_ + (((lane & 15) ^ (2 * (rl & 7))) << 2);
        }

        f32x4 acc[5];
#pragma unroll
        for (int mt = 0; mt < 5; mt++) acc[mt] = (f32x4){0.f, 0.f, 0.f, 0.f};

        {
            float* d0 = sb + wave * 768;
#pragma unroll
            for (int g = 0; g < 3; g++) glds16(gp[g], d0 + g * 256);
        }
        __syncthreads();

        for (int s = 0; s < 12; s++) {
            if (s < 11) {
                float* d0 = sb + ((s + 1) & 1) * 6144 + wave * 768;
#pragma unroll
                for (int g = 0; g < 3; g++) glds16(gp[g] + (s + 1) * 64, d0 + g * 256);
            }
            const float* bb = sb + (s & 1) * 6144;
#pragma unroll
            for (int ksg = 0; ksg < 2; ksg++) {
                s16x8 bf = *(const s16x8*)(wthi +
                           ((size_t)(wave * 24 + s * 2 + ksg) * 64 + lane) * 8);
                int kc = ksg * 8 + quad * 2;
#pragma unroll
                for (int mt = 0; mt < 5; mt++) {
                    int row = mt * 16 + m;
                    const float* fb = bb + row * 64 + ((kc ^ (2 * (row & 7))) << 2);
                    f32x4 lo = *(const f32x4*)fb, hi = *(const f32x4*)(fb + 4);
                    acc[mt] = __builtin_amdgcn_mfma_f32_16x16x32_bf16(
                        pack_bf16(lo, hi), bf, acc[mt], 0, 0, 0);
                }
            }
            __syncthreads();
        }

        float bv = bias[wave * 16 + m];
        float s0 = 0.f, s1 = 0.f;
#pragma unroll
        for (int mt = 0; mt < 5; mt++)
#pragma unroll
            for (int r = 0; r < 4; r++) {
                int prow = mt * 16 + quad * 4 + r;
                float v = acc[mt][r] + bv;
                acc[mt][r] = v;
                if (prow < 35) s0 += v * v;
                else if (prow < 70) s1 += v * v;
            }
        s0 += __shfl_xor(s0, 16); s0 += __shfl_xor(s0, 32);
        s1 += __shfl_xor(s1, 16); s1 += __shfl_xor(s1, 32);
        float sc0 = rsqrtf(fmaxf(s0, 1e-24f));
        float sc1 = rsqrtf(fmaxf(s1, 1e-24f));
        __syncthreads();
#pragma unroll
        for (int mt = 0; mt < 5; mt++)
#pragma unroll
            for (int r = 0; r < 4; r++) {
                int prow = mt * 16 + quad * 4 + r;
                if (prow < 70)
                    xb[prow * 136 + wave * 16 + m] =
                        f2bf(acc[mt][r] * (prow < 35 ? sc0 : sc1));
            }
        __syncthreads();
        unsigned short* qdst = qfrag + (size_t)qp * 10240;
#pragma unroll
        for (int i = 0; i < 3; i++) {
            int ch = t + i * 512;
            if (ch < 1280) {
                int ln = ch & 63;
                int prow = ((ch >> 8) << 4) + (ln & 15);
                int d0 = ((ch >> 6) & 3) * 32 + (ln >> 4) * 8;
                s16x8 v = (s16x8){0, 0, 0, 0, 0, 0, 0, 0};
                if (prow < 70) v = *(const s16x8*)&xb[prow * 136 + d0];
                *(s16x8*)&qdst[(size_t)ch * 8] = v;
            }
        }
    }
}

// ---------------- interact v5: mt-split ACROSS waves (8 waves, single nt-sweep each) ----
// R11 accounting: interact_v4 ~= 41 us vs an ~18-20 us floor; the slack is v4's TWO
// serial nt-sweeps per pass (mt-halves) on only 8 waves/CU. v5 assigns the halves to
// DIFFERENT waves: 512 threads, waves 0-3 compute mts 0-2, waves 4-7 compute mts 3-4
// for the same 4 qp per pass. Each wave: ONE nt-sweep, live set <= ~95 VGPR (a[3][4]=48
// + bfr 16 + rmax 12) -- spill-safe by construction. Partials combined via a 64 B LDS
// buffer + two uniform barriers per pass. Per-pass critical path ~halves; 16 waves/CU.
// MFMA core, fragment layouts, per-wave reduction trees, out-mapping identical to the
// R9-R11-verified lineage; only the final s = halfA + halfB association changes (f32
// noise). Staging: waves 0-3 stage 2 nt-tiles, waves 4-7 stage 1 (12 total, as before).
__global__ __launch_bounds__(512, 1) void interact_k(
    const unsigned short* __restrict__ qfrag, const unsigned short* __restrict__ pfrag,
    float* __restrict__ out) {
    __shared__ unsigned short plds[24576];           // 48 KB p-tile, shared by all 8 waves
    __shared__ float comb[2][4][2];                  // [half][wq][s0/s1]
    int wave = threadIdx.x >> 6, lane = threadIdx.x & 63;
    int b = blockIdx.x;                              // 768 blocks
    int xcd = b & 7, i = b >> 3;                     // i in [0,96)
    int c = xcd * 24 + (i % 24);                     // [0,192)
    int qgg = i / 24;                                // [0,4)
    int side = c / 96, pb = c - side * 96;
    int wq = wave & 3, half = wave >> 2;
    int m = lane & 15, quad = lane >> 4;

    const unsigned short* pbase = pfrag + (size_t)c * 24576;

    // stage p-tile: waves 0-3 take nt {w, w+8}; waves 4-7 take nt {w}
#pragma unroll
    for (int g = 0; g < 2; g++) {
        int nt = wave + g * 8;
        if (nt < 12) {
#pragma unroll
            for (int ks = 0; ks < 4; ks++)
                glds16(pbase + ((size_t)(nt * 4 + ks) * 64 + lane) * 8,
                       &plds[(size_t)(nt * 4 + ks) * 512]);
        }
    }
    __syncthreads();                                 // drain staging; plds read-only after

    const f32x4 zero4 = (f32x4){0.f, 0.f, 0.f, 0.f};

#pragma unroll 1
    for (int pass = 0; pass < 3; pass++) {
        int qp = (qgg * 3 + pass) * 4 + wq;          // [0,48)
        const unsigned short* qbase = qfrag + (size_t)qp * 10240;
        float s0 = 0.f, s1 = 0.f;

        if (half == 0) {
            // ---------- waves 0-3: mts 0..2 (live ~95 VGPR) ----------
            s16x8 a[3][4];
#pragma unroll
            for (int mt = 0; mt < 3; mt++)
#pragma unroll
                for (int ks = 0; ks < 4; ks++)
                    a[mt][ks] = *(const s16x8*)(qbase +
                                ((size_t)(mt * 4 + ks) * 64 + lane) * 8);
            float rmax[3][4];
#pragma unroll
            for (int mt = 0; mt < 3; mt++)
#pragma unroll
                for (int rr = 0; rr < 4; rr++) rmax[mt][rr] = NEGF;

            for (int nt = 0; nt < 12; nt++) {
                s16x8 bfr[4];
#pragma unroll
                for (int ks = 0; ks < 4; ks++)
                    bfr[ks] = *(const s16x8*)&plds[((size_t)(nt * 4 + ks) * 64 + lane) * 8];
                __builtin_amdgcn_s_setprio(1);
#pragma unroll
                for (int mt = 0; mt < 3; mt++) {
                    f32x4 acc = __builtin_amdgcn_mfma_f32_16x16x32_bf16(a[mt][0], bfr[0], zero4, 0, 0, 0);
                    acc = __builtin_amdgcn_mfma_f32_16x16x32_bf16(a[mt][1], bfr[1], acc, 0, 0, 0);
                    acc = __builtin_amdgcn_mfma_f32_16x16x32_bf16(a[mt][2], bfr[2], acc, 0, 0, 0);
                    acc = __builtin_amdgcn_mfma_f32_16x16x32_bf16(a[mt][3], bfr[3], acc, 0, 0, 0);
#pragma unroll
                    for (int rr = 0; rr < 4; rr++)
                        rmax[mt][rr] = fmaxf(rmax[mt][rr], acc[rr]);
                }
                __builtin_amdgcn_s_setprio(0);
            }
#pragma unroll
            for (int mt = 0; mt < 3; mt++)
#pragma unroll
                for (int rr = 0; rr < 4; rr++) {
                    float v = rmax[mt][rr];
                    v = fmaxf(v, __shfl_xor(v, 1));
                    v = fmaxf(v, __shfl_xor(v, 2));
                    v = fmaxf(v, __shfl_xor(v, 4));
                    v = fmaxf(v, __shfl_xor(v, 8));
                    int prow = mt * 16 + quad * 4 + rr;
                    if (prow < 35) s0 += v;
                    else if (prow < 70) s1 += v;
                }
        } else {
            // ---------- waves 4-7: mts 3..4 (live ~75 VGPR) ----------
            s16x8 a[2][4];
#pragma unroll
            for (int mt = 0; mt < 2; mt++)
#pragma unroll
                for (int ks = 0; ks < 4; ks++)
                    a[mt][ks] = *(const s16x8*)(qbase +
                                ((size_t)((mt + 3) * 4 + ks) * 64 + lane) * 8);
            float rmax[2][4];
#pragma unroll
            for (int mt = 0; mt < 2; mt++)
#pragma unroll
                for (int rr = 0; rr < 4; rr++) rmax[mt][rr] = NEGF;

            for (int nt = 0; nt < 12; nt++) {
                s16x8 bfr[4];
#pragma unroll
                for (int ks = 0; ks < 4; ks++)
                    bfr[ks] = *(const s16x8*)&plds[((size_t)(nt * 4 + ks) * 64 + lane) * 8];
                __builtin_amdgcn_s_setprio(1);
#pragma unroll
                for (int mt = 0; mt < 2; mt++) {
                    f32x4 acc = __builtin_amdgcn_mfma_f32_16x16x32_bf16(a[mt][0], bfr[0], zero4, 0, 0, 0);
                    acc = __builtin_amdgcn_mfma_f32_16x16x32_bf16(a[mt][1], bfr[1], acc, 0, 0, 0);
                    acc = __builtin_amdgcn_mfma_f32_16x16x32_bf16(a[mt][2], bfr[2], acc, 0, 0, 0);
                    acc = __builtin_amdgcn_mfma_f32_16x16x32_bf16(a[mt][3], bfr[3], acc, 0, 0, 0);
#pragma unroll
                    for (int rr = 0; rr < 4; rr++)
                        rmax[mt][rr] = fmaxf(rmax[mt][rr], acc[rr]);
                }
                __builtin_amdgcn_s_setprio(0);
            }
#pragma unroll
            for (int mt = 0; mt < 2; mt++)
#pragma unroll
                for (int rr = 0; rr < 4; rr++) {
                    float v = rmax[mt][rr];
                    v = fmaxf(v, __shfl_xor(v, 1));
                    v = fmaxf(v, __shfl_xor(v, 2));
                    v = fmaxf(v, __shfl_xor(v, 4));
                    v = fmaxf(v, __shfl_xor(v, 8));
                    int prow = (mt + 3) * 16 + quad * 4 + rr;
                    if (prow < 35) s0 += v;
                    else if (prow < 70) s1 += v;
                }
        }

        s0 += __shfl_xor(s0, 16); s0 += __shfl_xor(s0, 32);
        s1 += __shfl_xor(s1, 16); s1 += __shfl_xor(s1, 32);
        if (lane == 0) { comb[half][wq][0] = s0; comb[half][wq][1] = s1; }
        __syncthreads();                             // partials visible
        if (half == 0 && lane == 0) {
            int qb0 = qp * 2, qb1 = qp * 2 + 1;
            out[(size_t)qb0 * (2 * B_) + side * B_ + pb] = s0 + comb[1][wq][0];
            out[(size_t)qb1 * (2 * B_) + side * B_ + pb] = s1 + comb[1][wq][1];
        }
        __syncthreads();                             // protect comb before next pass
    }
}

// ---------------- launch ----------------
extern "C" void kernel_launch(void* const* d_in, const int* in_sizes, int n_in,
                              void* d_out, int out_size, void* d_ws, size_t ws_size,
                              hipStream_t stream) {
    const float* qh   = (const float*)d_in[0];
    const float* ph   = (const float*)d_in[1];
    const float* nh   = (const float*)d_in[2];
    const float* W    = (const float*)d_in[3];
    const float* bias = (const float*)d_in[4];
    const void* pmask = d_in[5];
    const void* nmask = d_in[6];
    float* out = (float*)d_out;
    char* ws = (char*)d_ws;

    constexpr size_t WTHI_OFF  = 256;                        // 196608 B
    constexpr size_t MASKC_OFF = WTHI_OFF + 196608;          // 34560 B
    constexpr size_t QFRAG_OFF = MASKC_OFF + 34560;          // 983040 B
    constexpr size_t PFRAG_OFF = QFRAG_OFF + 983040;         // 9437184 B

    unsigned short* wthi   = (unsigned short*)(ws + WTHI_OFF);
    unsigned char* maskc   = (unsigned char*)(ws + MASKC_OFF);
    unsigned short* qfrag  = (unsigned short*)(ws + QFRAG_OFF);
    unsigned short* pfrag  = (unsigned short*)(ws + PFRAG_OFF);

    prep_k<<<183, 256, 0, stream>>>(W, wthi, pmask, nmask, maskc);
    proj_k<<<240, 512, 0, stream>>>(qh, ph, nh, wthi, bias, maskc, qfrag, pfrag);
    interact_k<<<768, 512, 0, stream>>>(qfrag, pfrag, out);
}